// Round 5
// baseline (482.238 us; speedup 1.0000x reference)
//
#include <hip/hip_runtime.h>

// Instant-NGP hash-grid trilinear interp — persistent-block binned edition.
//
// Evidence so far: R1 unsorted gather = 612 MB L2-miss @ 3.37 TB/s, 190 us.
// R4 sorted-by-bin main got FETCH down to 274 MB (reuse capture works) but ran
// at 1.07 TB/s because occupancy fell to 33% (one short block per bin).
// The random-gather stream is rate-limited by requests in flight, so the
// fetch savings only pay at high occupancy.
//
// R5: (a) main = 2048 persistent blocks x 256 thr; each XCD (blockIdx&7) owns
// a contiguous 4096-bin Morton slab; each block loops over 16 bins, 128
// point-slots per pass -> dense waves, no per-bin dispatch overhead.
// (b) scatter = 2048 persistent blocks grid-striding points in order, so the
// resident window writes each bin's current slot line repeatedly -> merges in
// L2 (attacks R4's suspected random-write cost).
// Per-point math unchanged from the verified R1 kernel (bit-identical output,
// order-independent). Overflow list keeps correctness for any distribution.

#define TILE_SHIFT 3                 // tile = 8^3 cells
#define MDIM 32                      // Morton dims (tiles/dim = 25 <= 32)
#define NBINS (MDIM * MDIM * MDIM)   // 32768
#define CAP 192                      // slots per bin (avg occupancy ~128)
#define NBLK 2048                    // persistent blocks (8 XCD x 256)
#define BPB (NBINS / NBLK)           // 16 bins per block

__device__ __forceinline__ unsigned part1by2(unsigned x) {
    x &= 0x3Fu;
    x = (x | (x << 16)) & 0x030000FFu;
    x = (x | (x << 8))  & 0x0300F00Fu;
    x = (x | (x << 4))  & 0x030C30C3u;
    x = (x | (x << 2))  & 0x09249249u;
    return x;
}

__device__ __forceinline__ unsigned point_bin(float px, float py, float pz) {
    float qx = px / 0.005f, qy = py / 0.005f, qz = pz / 0.005f;
    int cx = (int)floorf(qx), cy = (int)floorf(qy), cz = (int)floorf(qz);
    unsigned tx = ((unsigned)cx) >> TILE_SHIFT;
    unsigned ty = ((unsigned)cy) >> TILE_SHIFT;
    unsigned tz = ((unsigned)cz) >> TILE_SHIFT;
    tx = min(tx, (unsigned)(MDIM - 1));
    ty = min(ty, (unsigned)(MDIM - 1));
    tz = min(tz, (unsigned)(MDIM - 1));
    return part1by2(tx) | (part1by2(ty) << 1) | (part1by2(tz) << 2);
}

// Core per-point math — identical to the verified R1 kernel.
__device__ __forceinline__ void interp_point(
    int i, unsigned h, const float* __restrict__ pts,
    const float4* __restrict__ feat4, float4* __restrict__ out4,
    unsigned buckets, int is_pow2)
{
    float px = pts[3*i], py = pts[3*i+1], pz = pts[3*i+2];
    float qx = px / 0.005f, qy = py / 0.005f, qz = pz / 0.005f;
    float bx = floorf(qx), by = floorf(qy), bz = floorf(qz);
    float fx = qx - bx, fy = qy - by, fz = qz - bz;
    unsigned ux = (unsigned)(int)bx, uy = (unsigned)(int)by, uz = (unsigned)(int)bz;
    unsigned hx0 = ux, hx1 = ux + 1u;
    unsigned hy0 = uy * 2654435761u, hy1 = (uy + 1u) * 2654435761u;
    unsigned hz0 = uz * 805459861u,  hz1 = (uz + 1u) * 805459861u;
    unsigned hsh[8] = {
        hx0 ^ hy0 ^ hz0, hx1 ^ hy0 ^ hz0,
        hx0 ^ hy1 ^ hz0, hx1 ^ hy1 ^ hz0,
        hx0 ^ hy0 ^ hz1, hx1 ^ hy0 ^ hz1,
        hx0 ^ hy1 ^ hz1, hx1 ^ hy1 ^ hz1,
    };
    unsigned off[8];
    if (is_pow2) {
        unsigned mask = buckets - 1u;
        #pragma unroll
        for (int c = 0; c < 8; ++c) off[c] = (hsh[c] & mask) * 2u + h;
    } else {
        #pragma unroll
        for (int c = 0; c < 8; ++c) off[c] = (hsh[c] % buckets) * 2u + h;
    }
    float4 f[8];
    #pragma unroll
    for (int c = 0; c < 8; ++c) f[c] = feat4[off[c]];
    float wx0 = 1.0f - fx, wx1 = fx;
    float wy0 = 1.0f - fy, wy1 = fy;
    float wz0 = 1.0f - fz, wz1 = fz;
    float w[8] = {
        (wx0 * wy0) * wz0, (wx1 * wy0) * wz0,
        (wx0 * wy1) * wz0, (wx1 * wy1) * wz0,
        (wx0 * wy0) * wz1, (wx1 * wy0) * wz1,
        (wx0 * wy1) * wz1, (wx1 * wy1) * wz1,
    };
    float4 a = make_float4(0.f, 0.f, 0.f, 0.f);
    #pragma unroll
    for (int c = 0; c < 8; ++c) {
        a.x += w[c] * f[c].x;
        a.y += w[c] * f[c].y;
        a.z += w[c] * f[c].z;
        a.w += w[c] * f[c].w;
    }
    out4[(size_t)i * 2u + h] = a;
}

// Scatter: persistent blocks stride points IN ORDER so the resident window's
// slot-line writes merge in L2 before eviction.
__global__ __launch_bounds__(256) void scatter_bin_kernel(
    const float* __restrict__ pts, unsigned* __restrict__ count,
    unsigned* __restrict__ ocount, unsigned* __restrict__ slots,
    unsigned* __restrict__ ovf, int N)
{
    int stride = gridDim.x * blockDim.x;
    for (int i = blockIdx.x * blockDim.x + threadIdx.x; i < N; i += stride) {
        unsigned b = point_bin(pts[3*i], pts[3*i+1], pts[3*i+2]);
        unsigned pos = atomicAdd(&count[b], 1u);
        if (pos < CAP) {
            slots[b * CAP + pos] = (unsigned)i;
        } else {
            unsigned o = atomicAdd(ocount, 1u);
            ovf[o] = (unsigned)i;
        }
    }
}

// Main: persistent blocks; XCD (orig&7) owns a contiguous Morton slab of
// 4096 bins; each block handles BPB bins, 128 point-slots per pass.
__global__ __launch_bounds__(256) void main_binned_kernel(
    const float* __restrict__ pts, const unsigned* __restrict__ count,
    const unsigned* __restrict__ slots, const float4* __restrict__ feat4,
    float4* __restrict__ out4, unsigned buckets, int is_pow2)
{
    int orig = blockIdx.x;                 // 0..NBLK-1
    int xcd  = orig & 7;
    int lq   = orig >> 3;                  // 0..255
    int bin0 = xcd * (NBINS / 8) + lq * BPB;

    unsigned s_in_blk = threadIdx.x >> 1;  // 0..127
    unsigned h = threadIdx.x & 1;

    for (int b = bin0; b < bin0 + BPB; ++b) {
        unsigned cnt = count[b];
        cnt = min(cnt, (unsigned)CAP);
        for (unsigned base = 0; base < cnt; base += 128u) {
            unsigned s = base + s_in_blk;
            if (s < cnt) {
                int i = (int)slots[(size_t)b * CAP + s];
                interp_point(i, h, pts, feat4, out4, buckets, is_pow2);
            }
        }
    }
}

// Overflow cleanup (normally 0 points).
__global__ __launch_bounds__(256) void overflow_kernel(
    const float* __restrict__ pts, const unsigned* __restrict__ ocount,
    const unsigned* __restrict__ ovf, const float4* __restrict__ feat4,
    float4* __restrict__ out4, unsigned buckets, int is_pow2)
{
    unsigned oc = *ocount;
    unsigned total = oc * 2u;
    unsigned stride = gridDim.x * blockDim.x;
    for (unsigned t = blockIdx.x * blockDim.x + threadIdx.x; t < total; t += stride) {
        int i = (int)ovf[t >> 1];
        interp_point(i, t & 1u, pts, feat4, out4, buckets, is_pow2);
    }
}

// Fallback (verified R1 kernel) if ws is too small.
__global__ __launch_bounds__(256) void ngp_hash_interp2(
    const float* __restrict__ pts, const float4* __restrict__ feat4,
    float4* __restrict__ out4, int N, unsigned buckets, int is_pow2)
{
    int t = blockIdx.x * blockDim.x + threadIdx.x;
    int i = t >> 1;
    unsigned h = (unsigned)(t & 1);
    if (i >= N) return;
    interp_point(i, h, pts, feat4, out4, buckets, is_pow2);
}

extern "C" void kernel_launch(void* const* d_in, const int* in_sizes, int n_in,
                              void* d_out, int out_size, void* d_ws, size_t ws_size,
                              hipStream_t stream) {
    const float* pts    = (const float*)d_in[0];
    const float4* feat4 = (const float4*)d_in[1];
    float4* out4 = (float4*)d_out;

    int N = in_sizes[0] / 3;
    unsigned buckets = (unsigned)(in_sizes[1] / 8);
    int is_pow2 = ((buckets & (buckets - 1u)) == 0u) ? 1 : 0;

    // ws layout: count u32[NBINS] | ocount u32 (+pad) | slots u32[NBINS*CAP]
    //            | ovf u32[N]
    const size_t off_oc    = (size_t)NBINS * 4;
    const size_t off_slots = off_oc + 256;
    const size_t off_ovf   = off_slots + (size_t)NBINS * CAP * 4;
    const size_t need      = off_ovf + (size_t)N * 4;

    if (ws_size < need || N <= 0) {
        const int block = 256;
        const long long total = 2LL * N;
        const int grid = (int)((total + block - 1) / block);
        if (grid > 0)
            hipLaunchKernelGGL(ngp_hash_interp2, dim3(grid), dim3(block), 0, stream,
                               pts, feat4, out4, N, buckets, is_pow2);
        return;
    }

    unsigned* count  = (unsigned*)d_ws;
    unsigned* ocount = (unsigned*)((char*)d_ws + off_oc);
    unsigned* slots  = (unsigned*)((char*)d_ws + off_slots);
    unsigned* ovf    = (unsigned*)((char*)d_ws + off_ovf);

    hipMemsetAsync(d_ws, 0, off_oc + 4, stream);   // clear count + ocount

    hipLaunchKernelGGL(scatter_bin_kernel, dim3(NBLK), dim3(256), 0, stream,
                       pts, count, ocount, slots, ovf, N);
    hipLaunchKernelGGL(main_binned_kernel, dim3(NBLK), dim3(256), 0, stream,
                       pts, count, slots, feat4, out4, buckets, is_pow2);
    hipLaunchKernelGGL(overflow_kernel, dim3(512), dim3(256), 0, stream,
                       pts, ocount, ovf, feat4, out4, buckets, is_pow2);
}

// Round 6
// 191.216 us; speedup vs baseline: 2.5220x; 2.5220x over previous
//
#include <hip/hip_runtime.h>

// Instant-NGP hash-grid trilinear interpolation — reverted to the Round-1
// kernel, which remains the fastest measured (190 us).
//
// Why this is (operationally) the ceiling, per R1-R5 evidence:
//  - The kernel is bound by the random 64B-line gather stream: 612 MB of
//    L2-miss traffic at ~3.37 TB/s, VALUBusy 3.5%, occupancy 81%. The stream
//    rate scales with resident waves (R4: 33% occ -> 1.07 TB/s), i.e. it is
//    in-flight-request-limited and already saturated at full occupancy.
//  - Instruction shape is irrelevant (R2: half the VMEM instructions, same
//    lines -> identical time).
//  - Spatial reordering cuts fetch to ~274 MB (R4) but every implementation
//    of the permutation costs more than it saves: random-write scatter hits
//    a ~0.8 TB/s wall (R3: 181 us), index-indirection kills occupancy or
//    locality (R4/R5), and a sorted main kernel randomizes the output writes
//    (~128 MB writeback) instead. Three attempts: 349/391/482 us vs 190.
//
// pts: (N,3) f32 in [0,1)^3; voxel_features: (buckets, 8) f32; out: (N,8) f32.

__global__ __launch_bounds__(256) void ngp_hash_interp(
    const float* __restrict__ pts,
    const float* __restrict__ feat,
    float* __restrict__ out,
    int N, unsigned buckets, int is_pow2)
{
    int i = blockIdx.x * blockDim.x + threadIdx.x;
    if (i >= N) return;

    float px = pts[3 * i + 0];
    float py = pts[3 * i + 1];
    float pz = pts[3 * i + 2];

    // f32 divide by the float closest to 0.005 — matches jnp pts / RES.
    float qx = px / 0.005f;
    float qy = py / 0.005f;
    float qz = pz / 0.005f;

    float bx = floorf(qx), by = floorf(qy), bz = floorf(qz);
    float fx = qx - bx, fy = qy - by, fz = qz - bz;

    // pts in [0,1) -> base in [0,199]; no negatives.
    unsigned ux = (unsigned)(int)bx;
    unsigned uy = (unsigned)(int)by;
    unsigned uz = (unsigned)(int)bz;

    unsigned hx0 = ux;                          // * PRIMES[0] == 1
    unsigned hx1 = ux + 1u;
    unsigned hy0 = uy * 2654435761u;            // PRIMES[1], uint32 wraparound
    unsigned hy1 = (uy + 1u) * 2654435761u;
    unsigned hz0 = uz * 805459861u;             // PRIMES[2]
    unsigned hz1 = (uz + 1u) * 805459861u;

    // Corner order x-fastest: c&1 = x, (c>>1)&1 = y, (c>>2)&1 = z
    unsigned h[8] = {
        hx0 ^ hy0 ^ hz0,
        hx1 ^ hy0 ^ hz0,
        hx0 ^ hy1 ^ hz0,
        hx1 ^ hy1 ^ hz0,
        hx0 ^ hy0 ^ hz1,
        hx1 ^ hy0 ^ hz1,
        hx0 ^ hy1 ^ hz1,
        hx1 ^ hy1 ^ hz1,
    };

    unsigned slot[8];
    if (is_pow2) {
        unsigned mask = buckets - 1u;
        #pragma unroll
        for (int c = 0; c < 8; ++c) slot[c] = h[c] & mask;
    } else {
        #pragma unroll
        for (int c = 0; c < 8; ++c) slot[c] = h[c] % buckets;
    }

    // Issue all 16 float4 gathers before consuming any -> 16 loads in flight.
    float4 f0[8], f1[8];
    #pragma unroll
    for (int c = 0; c < 8; ++c) {
        const float4* fp = (const float4*)(feat + (size_t)slot[c] * 8u);
        f0[c] = fp[0];
        f1[c] = fp[1];
    }

    float wx0 = 1.0f - fx, wx1 = fx;
    float wy0 = 1.0f - fy, wy1 = fy;
    float wz0 = 1.0f - fz, wz1 = fz;
    // Same multiply order as reference: (wx*wy)*wz
    float w[8] = {
        (wx0 * wy0) * wz0, (wx1 * wy0) * wz0,
        (wx0 * wy1) * wz0, (wx1 * wy1) * wz0,
        (wx0 * wy0) * wz1, (wx1 * wy0) * wz1,
        (wx0 * wy1) * wz1, (wx1 * wy1) * wz1,
    };

    float4 a0 = make_float4(0.f, 0.f, 0.f, 0.f);
    float4 a1 = make_float4(0.f, 0.f, 0.f, 0.f);
    #pragma unroll
    for (int c = 0; c < 8; ++c) {   // summation order k = 0..7, matches einsum
        a0.x += w[c] * f0[c].x;
        a0.y += w[c] * f0[c].y;
        a0.z += w[c] * f0[c].z;
        a0.w += w[c] * f0[c].w;
        a1.x += w[c] * f1[c].x;
        a1.y += w[c] * f1[c].y;
        a1.z += w[c] * f1[c].z;
        a1.w += w[c] * f1[c].w;
    }

    float4* op = (float4*)(out + (size_t)i * 8u);
    op[0] = a0;
    op[1] = a1;
}

extern "C" void kernel_launch(void* const* d_in, const int* in_sizes, int n_in,
                              void* d_out, int out_size, void* d_ws, size_t ws_size,
                              hipStream_t stream) {
    const float* pts  = (const float*)d_in[0];
    const float* feat = (const float*)d_in[1];
    float* out = (float*)d_out;

    int N = in_sizes[0] / 3;
    unsigned buckets = (unsigned)(in_sizes[1] / 8);
    int is_pow2 = ((buckets & (buckets - 1u)) == 0u) ? 1 : 0;

    const int block = 256;
    const int grid = (N + block - 1) / block;
    hipLaunchKernelGGL(ngp_hash_interp, dim3(grid), dim3(block), 0, stream,
                       pts, feat, out, N, buckets, is_pow2);
}